// Round 7
// baseline (541.234 us; speedup 1.0000x reference)
//
#include <hip/hip_runtime.h>
#include <hip/hip_bf16.h>

#define N_ATOMS 10000
#define N_PAIRS 100000
#define HH 64
#define MAXZ 100

// ---- expnormal rbf constants ----
constexpr float RBF_START = 0.6065306597126334f;               // exp(-0.5)
constexpr float RBF_STEP  = (1.0f - RBF_START) / 31.0f;        // linspace step
constexpr float RBF_BETA  = 1.0f / ((0.0625f * (1.0f - RBF_START)) * (0.0625f * (1.0f - RBF_START)));
constexpr float LOG2E     = 1.4426950408889634f;
constexpr float NEG_ALPHA_L2 = -10.0f * LOG2E;                 // exp(-10d) = 2^(NEG_ALPHA_L2*d)
constexpr float NEG_BETA_L2  = -RBF_BETA * LOG2E;              // exp(-b t^2) = 2^(NEG_BETA_L2*t^2)

// ---- f32 param layout in workspace (element offsets) ----
#define OFF_EMB   0
#define OFF_W2    6400
#define OFF_B2    14592
#define OFF_D1W   14656
#define OFF_D1B   16704
#define OFF_D2W   16768
#define OFF_D2B   18816
#define OFF_D3W   18880
#define OFF_D3B   20928
#define OFF_LT0   20992
#define OFF_LT1   25088
#define OFF_LT2   29184
#define OFF_L1W   33280
#define OFF_L1B   41472
#define OFF_L2W   41600
#define OFF_L2B   66176
#define OFF_LNG   66368
#define OFF_LNB   66432
#define N_PARAMF  66496

// ws byte offsets
#define WS_WF     0
#define WS_CNT    270336
#define WS_OFF    311296
#define WS_CUR    352256
#define WS_FLAGS  393216
#define WS_T1     397312
#define WS_T2     425984
#define WS_DPK    458752
#define WS_ZNL    2058752

__device__ __forceinline__ float bf2f(unsigned short u) {
    return __uint_as_float(((unsigned int)u) << 16);
}

// ---- on-device buffer layout probe (see round 3/4 forensics) ----
__device__ int classify64(const unsigned short* b, int lane) {
    unsigned short x = b[lane];
    int e = (x >> 7) & 0xFF;
    bool implaus = (x != 0) && (e < 96 || e > 133);
    bool zeroeven = ((lane & 1) == 0) && (x == 0);
    unsigned long long mi = __ballot(implaus);
    unsigned long long mz = __ballot(zeroeven);
    if (__popcll(mz) == 32) return 0;   // bf16-rounded f32 layout
    if (__popcll(mi) >= 8) return 0;    // raw f32 layout
    return 1;                           // true bf16 array
}

__global__ void k_probe(const unsigned short* emb_u, const unsigned short* dij_u,
                        const unsigned short* rij_u, int* flags) {
    int lane = threadIdx.x;
    int fp = classify64(emb_u, lane);
    int fd = classify64(dij_u, lane);
    int fr = classify64(rij_u, lane);
    if (lane == 0) { flags[0] = fp; flags[1] = fd; flags[2] = fr; }
}

struct ConvArgs { const void* src[18]; float* dst; };

__global__ void k_conv(ConvArgs a, const int* __restrict__ flags) {
    const int sizes[18] = {6400,8192,64,2048,64,2048,64,2048,64,4096,4096,4096,8192,128,24576,192,64,64};
    int t = blockIdx.x * 256 + threadIdx.x;
    if (t >= N_PARAMF) return;
    int acc = 0, seg = 0, off = t;
    #pragma unroll
    for (int i = 0; i < 18; ++i) {
        if (t >= acc && t < acc + sizes[i]) { seg = i; off = t - acc; }
        acc += sizes[i];
    }
    if (flags[0] == 1)
        a.dst[t] = bf2f(((const unsigned short*)a.src[seg])[off]);
    else
        a.dst[t] = ((const float*)a.src[seg])[off];
}

// T1[z][h] = sum_k W2[h][k]*emb[z][k]; T2[z][h] = sum_k W2[h][64+k]*emb[z][k]
__global__ void k_tab(const float* __restrict__ WF, float* __restrict__ T1, float* __restrict__ T2) {
    int z = blockIdx.x;
    int h = threadIdx.x;
    const float* ez = WF + OFF_EMB + z * HH;
    const float* w2 = WF + OFF_W2 + h * 128;
    float s1 = 0.f, s2 = 0.f;
    #pragma unroll
    for (int k = 0; k < 64; ++k) {
        float e = ez[k];
        s1 += w2[k] * e;
        s2 += w2[64 + k] * e;
    }
    T1[z * HH + h] = s1;
    T2[z * HH + h] = s2;
}

__global__ void k_count(const int* __restrict__ pidx, int* __restrict__ cnt) {
    int p = blockIdx.x * 256 + threadIdx.x;
    if (p < N_PAIRS) atomicAdd(&cnt[pidx[p]], 1);
}

__global__ void k_scan(const int* __restrict__ cnt, int* __restrict__ offs, int* __restrict__ cur) {
    __shared__ int buf[1024];
    int tid = threadIdx.x;
    int base = tid * 10;
    int c[10]; int s = 0;
    #pragma unroll
    for (int i = 0; i < 10; ++i) {
        int idx = base + i;
        int v = (idx < N_ATOMS) ? cnt[idx] : 0;
        c[i] = v; s += v;
    }
    buf[tid] = s;
    __syncthreads();
    for (int off = 1; off < 1024; off <<= 1) {
        int v = (tid >= off) ? buf[tid - off] : 0;
        __syncthreads();
        buf[tid] += v;
        __syncthreads();
    }
    int run = buf[tid] - s;
    #pragma unroll
    for (int i = 0; i < 10; ++i) {
        int idx = base + i;
        if (idx < N_ATOMS) { offs[idx] = run; cur[idx] = run; run += c[i]; }
    }
    if (tid == 0) offs[N_ATOMS] = N_PAIRS;
}

// fully pair-parallel: all gathers + dtype decode happen HERE (latency hidden
// by massive TLP), emitting plist-ordered contiguous streams for k_atom.
__global__ void k_fill(const int* __restrict__ pidx, const int* __restrict__ an,
                       const void* __restrict__ dij_v, const void* __restrict__ rij_v,
                       const int* __restrict__ flags,
                       int* __restrict__ cur,
                       float4* __restrict__ dpack, int* __restrict__ znl) {
    int p = blockIdx.x * 256 + threadIdx.x;
    if (p >= N_PAIRS) return;
    int s = pidx[p];
    int dst = pidx[N_PAIRS + p];
    int pos = atomicAdd(&cur[s], 1);
    float d, rx, ry, rz;
    if (flags[1] == 1) d = bf2f(((const unsigned short*)dij_v)[p]);
    else               d = ((const float*)dij_v)[p];
    if (flags[2] == 1) {
        const unsigned short* r = (const unsigned short*)rij_v;
        rx = bf2f(r[3*p]); ry = bf2f(r[3*p+1]); rz = bf2f(r[3*p+2]);
    } else {
        const float* r = (const float*)rij_v;
        rx = r[3*p]; ry = r[3*p+1]; rz = r[3*p+2];
    }
    dpack[pos] = make_float4(rx, ry, rz, d);
    znl[pos] = an[dst];
}

__device__ __forceinline__ float dot4(float4 a, float4 b) {
    return a.x*b.x + a.y*b.y + a.z*b.z + a.w*b.w;
}
__device__ __forceinline__ float fexp2(float x) { return __builtin_amdgcn_exp2f(x); }
__device__ __forceinline__ float fcos2pi(float x) { return __builtin_amdgcn_cosf(x); } // v_cos: cos(2*pi*x)
__device__ __forceinline__ float fsilu(float x) { return x / (1.0f + fexp2(-LOG2E * x)); }

// 4 waves/block, one atom per wave, 4 blocks/CU. Pair loop reads only
// contiguous streams (dpack/znl) + L1-resident T2 row; no gather chains.
__global__ __launch_bounds__(256, 4) void k_atom(
    const int* __restrict__ an,
    const float* __restrict__ WF,
    const int* __restrict__ offs,
    const float4* __restrict__ dpack, const int* __restrict__ znl,
    const float* __restrict__ T1, const float* __restrict__ T2,
    float* __restrict__ out)
{
    const int wave = threadIdx.x >> 6;
    const int h    = threadIdx.x & 63;
    const int n    = blockIdx.x * 4 + wave;

    // per-wave LDS slice: rbf 32 | nv 64 | y1 128 | y2 192 | accL 640 | ob 576 = 1632 (+pad)
    __shared__ __align__(16) float lds[4 * 1664];
    float* rbf  = lds + wave * 1664;
    float* nv   = rbf + 32;
    float* y1   = nv + 64;
    float* y2   = y1 + 128;
    float* accL = y2 + 192;
    float* ob   = accL + 640;

    // loop-invariant per-lane dp rows -> registers (24 x float4)
    const float4* d1r = (const float4*)(WF + OFF_D1W) + h * 8;
    const float4* d2r = (const float4*)(WF + OFF_D2W) + h * 8;
    const float4* d3r = (const float4*)(WF + OFF_D3W) + h * 8;
    float4 A1[8], A2[8], A3[8];
    #pragma unroll
    for (int i = 0; i < 8; ++i) { A1[i] = d1r[i]; A2[i] = d2r[i]; A3[i] = d3r[i]; }

    const float ed1 = (WF + OFF_D1B)[h];
    const float ed2 = (WF + OFF_D2B)[h];
    const float ed3 = (WF + OFF_D3B)[h];
    // Zij[h] = eb2[h] + T1[z_src][h] + T2[z_dst][h]
    const float zA  = (WF + OFF_B2)[h] + T1[an[n] * HH + h];

    float Is=0.f, sx=0.f, sy=0.f, sz=0.f;
    float Sxx=0.f, Syy=0.f, Szz=0.f, Sxy=0.f, Sxz=0.f, Syz=0.f;

    const int pbeg = offs[n], pend = offs[n + 1];

    // T2 row prefetch, 1 iteration deep
    float t2cur = (pbeg < pend) ? T2[znl[pbeg] * HH + h] : 0.f;

    for (int ii = pbeg; ii < pend; ++ii) {
        float4 dp = dpack[ii];                     // broadcast (wave-uniform)
        float t2nxt = (ii + 1 < pend) ? T2[znl[ii + 1] * HH + h] : 0.f;

        float d = dp.w;
        float inv = 1.0f / d;
        float ux = dp.x*inv, uy = dp.y*inv, uz = dp.z*inv;
        float rc = (d < 0.5f) ? 0.5f * (fcos2pi(d) + 1.0f) : 0.0f;

        if (h < 32) {
            float en = fexp2(NEG_ALPHA_L2 * d);
            float t = en - (RBF_START + RBF_STEP * (float)h);
            rbf[h] = fexp2(NEG_BETA_L2 * t * t) * rc;
        }
        __builtin_amdgcn_wave_barrier();

        float zc = zA + t2cur;

        float g1 = ed1, g2 = ed2, g3 = ed3;
        const float4* rb4 = (const float4*)rbf;
        #pragma unroll
        for (int r4 = 0; r4 < 8; ++r4) {
            float4 rb = rb4[r4];
            g1 += dot4(A1[r4], rb);
            g2 += dot4(A2[r4], rb);
            g3 += dot4(A3[r4], rb);
        }
        float Cc = rc * zc;
        float f1 = g1 * Cc;
        float f2 = g2 * Cc * 10.0f;
        float f3 = g3 * Cc * 100.0f;

        Is += f1;
        sx += f2 * ux;  sy += f2 * uy;  sz += f2 * uz;
        float q = (ux*ux + uy*uy + uz*uz) * (1.0f / 3.0f);
        Sxx += f3 * (ux*ux - q);
        Syy += f3 * (uy*uy - q);
        Szz += f3 * (uz*uz - q);
        Sxy += f3 * (ux*uy);
        Sxz += f3 * (ux*uz);
        Syz += f3 * (uy*uz);
        __builtin_amdgcn_wave_barrier();
        t2cur = t2nxt;
    }

    // ---- epilogue (uniform across waves; __syncthreads safe) ----
    accL[       h] = Is;
    accL[ 64  + h] = sx;  accL[128 + h] = sy;  accL[192 + h] = sz;
    accL[256 + h] = Sxx; accL[320 + h] = Syy; accL[384 + h] = Szz;
    accL[448 + h] = Sxy; accL[512 + h] = Sxz; accL[576 + h] = Syz;

    float tn = 3.0f*Is*Is + 2.0f*(sx*sx + sy*sy + sz*sz)
             + Sxx*Sxx + Syy*Syy + Szz*Szz
             + 2.0f*(Sxy*Sxy + Sxz*Sxz + Syz*Syz);

    float s1 = tn, s2 = tn * tn;
    #pragma unroll
    for (int o = 32; o > 0; o >>= 1) {
        s1 += __shfl_xor(s1, o);
        s2 += __shfl_xor(s2, o);
    }
    float mu  = s1 * (1.0f / 64.0f);
    float var = s2 * (1.0f / 64.0f) - mu * mu;
    float xh = (tn - mu) * rsqrtf(var + 1e-5f) * (WF + OFF_LNG)[h] + (WF + OFF_LNB)[h];
    nv[h] = xh;
    __syncthreads();

    #pragma unroll
    for (int jj = 0; jj < 2; ++jj) {
        int j = h + 64 * jj;
        const float4* wr = (const float4*)(WF + OFF_L1W) + j * 16;
        const float4* x4 = (const float4*)nv;
        float acc = (WF + OFF_L1B)[j];
        #pragma unroll
        for (int k4 = 0; k4 < 16; ++k4) acc += dot4(wr[k4], x4[k4]);
        y1[j] = fsilu(acc);
    }
    __syncthreads();

    #pragma unroll
    for (int mm = 0; mm < 3; ++mm) {
        int m = h + 64 * mm;
        const float4* wr = (const float4*)(WF + OFF_L2W) + m * 32;
        const float4* x4 = (const float4*)y1;
        float acc = (WF + OFF_L2B)[m];
        #pragma unroll
        for (int k4 = 0; k4 < 32; ++k4) acc += dot4(wr[k4], x4[k4]);
        y2[m] = fsilu(acc);
    }
    __syncthreads();

    float n0 = y2[3*h], n1 = y2[3*h+1], n2 = y2[3*h+2];
    const float4* t0r = (const float4*)(WF + OFF_LT0) + h * 16;
    const float4* t1r = (const float4*)(WF + OFF_LT1) + h * 16;
    const float4* t2r = (const float4*)(WF + OFF_LT2) + h * 16;
    const float4* aI  = (const float4*)(accL);
    const float4* aAx = (const float4*)(accL + 64);
    const float4* aAy = (const float4*)(accL + 128);
    const float4* aAz = (const float4*)(accL + 192);
    const float4* aXX = (const float4*)(accL + 256);
    const float4* aYY = (const float4*)(accL + 320);
    const float4* aZZ = (const float4*)(accL + 384);
    const float4* aXY = (const float4*)(accL + 448);
    const float4* aXZ = (const float4*)(accL + 512);
    const float4* aYZ = (const float4*)(accL + 576);

    float P0=0.f, PAx=0.f, PAy=0.f, PAz=0.f;
    float Q0=0.f, Q1=0.f, Q2=0.f, Q3=0.f, Q4=0.f, Q5=0.f;
    #pragma unroll
    for (int k4 = 0; k4 < 16; ++k4) {
        float4 w0 = t0r[k4], w1 = t1r[k4], w2 = t2r[k4];
        P0  += dot4(w0, aI[k4]);
        PAx += dot4(w1, aAx[k4]);
        PAy += dot4(w1, aAy[k4]);
        PAz += dot4(w1, aAz[k4]);
        Q0  += dot4(w2, aXX[k4]);
        Q1  += dot4(w2, aYY[k4]);
        Q2  += dot4(w2, aZZ[k4]);
        Q3  += dot4(w2, aXY[k4]);
        Q4  += dot4(w2, aXZ[k4]);
        Q5  += dot4(w2, aYZ[k4]);
    }
    float Iv = P0 * n0;
    float Ax = PAx * n1, Ay = PAy * n1, Az = PAz * n1;
    float Xx = Q0 * n2, Yy = Q1 * n2, Zz = Q2 * n2;
    float Xy = Q3 * n2, Xz = Q4 * n2, Yz = Q5 * n2;

    float* o = ob + h * 9;
    o[0] =  Iv + Xx;  o[1] = -Az + Xy;  o[2] =  Ay + Xz;
    o[3] =  Az + Xy;  o[4] =  Iv + Yy;  o[5] = -Ax + Yz;
    o[6] = -Ay + Xz;  o[7] =  Ax + Yz;  o[8] =  Iv + Zz;
    __syncthreads();

    float* outp = out + (size_t)n * 576;
    #pragma unroll
    for (int t = h; t < 576; t += 64) outp[t] = ob[t];
}

extern "C" void kernel_launch(void* const* d_in, const int* in_sizes, int n_in,
                              void* d_out, int out_size, void* d_ws, size_t ws_size,
                              hipStream_t stream) {
    const int* an   = (const int*)d_in[0];
    const int* pidx = (const int*)d_in[1];

    char* ws = (char*)d_ws;
    float*  WF    = (float*)(ws + WS_WF);
    int*    cnt   = (int*)(ws + WS_CNT);
    int*    offs  = (int*)(ws + WS_OFF);
    int*    cur   = (int*)(ws + WS_CUR);
    int*    flags = (int*)(ws + WS_FLAGS);
    float*  T1    = (float*)(ws + WS_T1);
    float*  T2    = (float*)(ws + WS_T2);
    float4* dpack = (float4*)(ws + WS_DPK);
    int*    znl   = (int*)(ws + WS_ZNL);
    float*  out   = (float*)d_out;

    hipMemsetAsync(cnt, 0, N_ATOMS * sizeof(int), stream);

    k_probe<<<1, 64, 0, stream>>>((const unsigned short*)d_in[4],
                                  (const unsigned short*)d_in[2],
                                  (const unsigned short*)d_in[3], flags);

    ConvArgs ca;
    for (int i = 0; i < 18; ++i) ca.src[i] = d_in[4 + i];
    ca.dst = WF;
    k_conv<<<(N_PARAMF + 255) / 256, 256, 0, stream>>>(ca, flags);
    k_tab<<<MAXZ, 64, 0, stream>>>(WF, T1, T2);

    k_count<<<(N_PAIRS + 255) / 256, 256, 0, stream>>>(pidx, cnt);
    k_scan<<<1, 1024, 0, stream>>>(cnt, offs, cur);
    k_fill<<<(N_PAIRS + 255) / 256, 256, 0, stream>>>(pidx, an, d_in[2], d_in[3],
                                                      flags, cur, dpack, znl);
    k_atom<<<2500, 256, 0, stream>>>(an, WF, offs, dpack, znl, T1, T2, out);
}

// Round 8
// 400.019 us; speedup vs baseline: 1.3530x; 1.3530x over previous
//
#include <hip/hip_runtime.h>
#include <hip/hip_bf16.h>

#define N_ATOMS 10000
#define N_PAIRS 100000
#define HH 64
#define MAXZ 100

typedef _Float16 h2_t __attribute__((ext_vector_type(2)));

// ---- expnormal rbf constants ----
constexpr float RBF_START = 0.6065306597126334f;
constexpr float RBF_STEP  = (1.0f - RBF_START) / 31.0f;
constexpr float RBF_BETA  = 1.0f / ((0.0625f * (1.0f - RBF_START)) * (0.0625f * (1.0f - RBF_START)));
constexpr float LOG2E     = 1.4426950408889634f;
constexpr float NEG_ALPHA_L2 = -10.0f * LOG2E;
constexpr float NEG_BETA_L2  = -RBF_BETA * LOG2E;

// ---- f32 param layout in workspace (element offsets) ----
#define OFF_EMB   0
#define OFF_W2    6400
#define OFF_B2    14592
#define OFF_D1W   14656
#define OFF_D1B   16704
#define OFF_D2W   16768
#define OFF_D2B   18816
#define OFF_D3W   18880
#define OFF_D3B   20928
#define OFF_LT0   20992
#define OFF_LT1   25088
#define OFF_LT2   29184
#define OFF_L1W   33280
#define OFF_L1B   41472
#define OFF_L2W   41600
#define OFF_L2B   66176
#define OFF_LNG   66368
#define OFF_LNB   66432
#define N_PARAMF  66496

// ws byte offsets
#define WS_WF     0
#define WS_CNT    270336
#define WS_OFF    311296
#define WS_CUR    352256
#define WS_T1     397312
#define WS_T2     425984
#define WS_DPK    458752
#define WS_ZNL    2058752

__device__ __forceinline__ float bf2f(unsigned short u) {
    return __uint_as_float(((unsigned int)u) << 16);
}
__device__ __forceinline__ float fexp2(float x) { return __builtin_amdgcn_exp2f(x); }
__device__ __forceinline__ float fcos2pi(float x) { return __builtin_amdgcn_cosf(x); }
__device__ __forceinline__ float fsilu(float x) { return x / (1.0f + fexp2(-LOG2E * x)); }
__device__ __forceinline__ h2_t u2h(unsigned u) { return __builtin_bit_cast(h2_t, u); }

#if __has_builtin(__builtin_amdgcn_fdot2)
__device__ __forceinline__ float FDOT2(h2_t a, h2_t b, float c) {
    return __builtin_amdgcn_fdot2(a, b, c, false);
}
#else
__device__ __forceinline__ float FDOT2(h2_t a, h2_t b, float c) {
    return c + (float)a.x * (float)b.x + (float)a.y * (float)b.y;
}
#endif

// ---- on-device buffer layout probe (see round 3/4 forensics) ----
// 1 = true bf16 (u16) array, 0 = f32 layout (raw or bf16-rounded values).
__device__ int classify64(const unsigned short* b, int lane) {
    unsigned short x = b[lane];
    int e = (x >> 7) & 0xFF;
    bool implaus = (x != 0) && (e < 96 || e > 133);
    bool zeroeven = ((lane & 1) == 0) && (x == 0);
    unsigned long long mi = __ballot(implaus);
    unsigned long long mz = __ballot(zeroeven);
    if (__popcll(mz) == 32) return 0;
    if (__popcll(mi) >= 8) return 0;
    return 1;
}

struct ConvArgs { const void* src[18]; float* dst; };

// param upconvert + cnt zeroing + inline param-layout classify
__global__ void k_conv(ConvArgs a, int* __restrict__ cnt) {
    const int sizes[18] = {6400,8192,64,2048,64,2048,64,2048,64,4096,4096,4096,8192,128,24576,192,64,64};
    __shared__ int fl;
    if (threadIdx.x < 64) {
        int f = classify64((const unsigned short*)a.src[0], threadIdx.x);
        if (threadIdx.x == 0) fl = f;
    }
    __syncthreads();
    int t = blockIdx.x * 256 + threadIdx.x;
    if (t < N_ATOMS) cnt[t] = 0;
    if (t >= N_PARAMF) return;
    int acc = 0, seg = 0, off = t;
    #pragma unroll
    for (int i = 0; i < 18; ++i) {
        if (t >= acc && t < acc + sizes[i]) { seg = i; off = t - acc; }
        acc += sizes[i];
    }
    if (fl == 1) a.dst[t] = bf2f(((const unsigned short*)a.src[seg])[off]);
    else         a.dst[t] = ((const float*)a.src[seg])[off];
}

// T1[z][h] = sum_k W2[h][k]*emb[z][k]; T2[z][h] = sum_k W2[h][64+k]*emb[z][k]
__global__ void k_tab(const float* __restrict__ WF, float* __restrict__ T1, float* __restrict__ T2) {
    int z = blockIdx.x;
    int h = threadIdx.x;
    const float* ez = WF + OFF_EMB + z * HH;
    const float* w2 = WF + OFF_W2 + h * 128;
    float s1 = 0.f, s2 = 0.f;
    #pragma unroll
    for (int k = 0; k < 64; ++k) {
        float e = ez[k];
        s1 += w2[k] * e;
        s2 += w2[64 + k] * e;
    }
    T1[z * HH + h] = s1;
    T2[z * HH + h] = s2;
}

__global__ void k_count(const int* __restrict__ pidx, int* __restrict__ cnt) {
    int p = blockIdx.x * 256 + threadIdx.x;
    if (p < N_PAIRS) atomicAdd(&cnt[pidx[p]], 1);
}

__global__ void k_scan(const int* __restrict__ cnt, int* __restrict__ offs, int* __restrict__ cur) {
    __shared__ int buf[1024];
    int tid = threadIdx.x;
    int base = tid * 10;
    int c[10]; int s = 0;
    #pragma unroll
    for (int i = 0; i < 10; ++i) {
        int idx = base + i;
        int v = (idx < N_ATOMS) ? cnt[idx] : 0;
        c[i] = v; s += v;
    }
    buf[tid] = s;
    __syncthreads();
    for (int off = 1; off < 1024; off <<= 1) {
        int v = (tid >= off) ? buf[tid - off] : 0;
        __syncthreads();
        buf[tid] += v;
        __syncthreads();
    }
    int run = buf[tid] - s;
    #pragma unroll
    for (int i = 0; i < 10; ++i) {
        int idx = base + i;
        if (idx < N_ATOMS) { offs[idx] = run; cur[idx] = run; run += c[i]; }
    }
    if (tid == 0) offs[N_ATOMS] = N_PAIRS;
}

// pair-parallel gather/decode into plist-ordered contiguous streams
__global__ void k_fill(const int* __restrict__ pidx, const int* __restrict__ an,
                       const void* __restrict__ dij_v, const void* __restrict__ rij_v,
                       int* __restrict__ cur,
                       float4* __restrict__ dpack, int* __restrict__ znl) {
    __shared__ int fdr[2];
    if (threadIdx.x < 64) {
        int fd = classify64((const unsigned short*)dij_v, threadIdx.x);
        int fr = classify64((const unsigned short*)rij_v, threadIdx.x);
        if (threadIdx.x == 0) { fdr[0] = fd; fdr[1] = fr; }
    }
    __syncthreads();
    int p = blockIdx.x * 256 + threadIdx.x;
    if (p >= N_PAIRS) return;
    int s = pidx[p];
    int dst = pidx[N_PAIRS + p];
    int pos = atomicAdd(&cur[s], 1);
    float d, rx, ry, rz;
    if (fdr[0] == 1) d = bf2f(((const unsigned short*)dij_v)[p]);
    else             d = ((const float*)dij_v)[p];
    if (fdr[1] == 1) {
        const unsigned short* r = (const unsigned short*)rij_v;
        rx = bf2f(r[3*p]); ry = bf2f(r[3*p+1]); rz = bf2f(r[3*p+2]);
    } else {
        const float* r = (const float*)rij_v;
        rx = r[3*p]; ry = r[3*p+1]; rz = r[3*p+2];
    }
    dpack[pos] = make_float4(rx, ry, rz, d);
    znl[pos] = an[dst];
}

__device__ __forceinline__ float dot4(float4 a, float4 b) {
    return a.x*b.x + a.y*b.y + a.z*b.z + a.w*b.w;
}

// 4 waves/block, one atom per wave. fp16-packed dp rows (48 VGPRs), fdot2 core.
__global__ __launch_bounds__(256, 3) void k_atom(
    const int* __restrict__ an,
    const float* __restrict__ WF,
    const int* __restrict__ offs,
    const float4* __restrict__ dpack, const int* __restrict__ znl,
    const float* __restrict__ T1, const float* __restrict__ T2,
    float* __restrict__ out)
{
    const int wave = threadIdx.x >> 6;
    const int h    = threadIdx.x & 63;
    const int n    = blockIdx.x * 4 + wave;

    // per-wave slice: rbfh 16 | nv 64 | y1 128 | y2 192 | accL 640 | ob 576 = 1616 (+pad)
    __shared__ __align__(16) float lds[4 * 1664];
    float* slice = lds + wave * 1664;
    float* rbfs  = slice;          // 64 B of fp16 rbf (32 halves)
    float* nv    = slice + 16;
    float* y1    = slice + 80;
    float* y2    = slice + 208;
    float* accL  = slice + 400;
    float* ob    = slice + 1040;
    _Float16* rbfh = (_Float16*)rbfs;

    // pack the three 32-wide dp rows for this lane as fp16 pairs (exact: weights are bf16-valued)
    h2_t AH1[16], AH2[16], AH3[16];
    {
        const float* w1 = WF + OFF_D1W + h * 32;
        const float* w2 = WF + OFF_D2W + h * 32;
        const float* w3 = WF + OFF_D3W + h * 32;
        #pragma unroll
        for (int i = 0; i < 16; ++i) {
            h2_t a, b, c;
            a.x = (_Float16)w1[2*i]; a.y = (_Float16)w1[2*i+1];
            b.x = (_Float16)w2[2*i]; b.y = (_Float16)w2[2*i+1];
            c.x = (_Float16)w3[2*i]; c.y = (_Float16)w3[2*i+1];
            AH1[i] = a; AH2[i] = b; AH3[i] = c;
        }
    }

    const float ed1 = (WF + OFF_D1B)[h];
    const float ed2 = (WF + OFF_D2B)[h];
    const float ed3 = (WF + OFF_D3B)[h];
    const float zA  = (WF + OFF_B2)[h] + T1[an[n] * HH + h];

    float Is=0.f, sx=0.f, sy=0.f, sz=0.f;
    float Sxx=0.f, Syy=0.f, Szz=0.f, Sxy=0.f, Sxz=0.f, Syz=0.f;

    const int pbeg = offs[n], pend = offs[n + 1];

    // 2-deep pipeline on znl, 1-deep on T2 row + dpack
    float4 dp_cur = make_float4(0.f, 0.f, 0.f, 1.f);
    float  t2cur  = 0.f;
    int    zn_n   = 0;
    if (pbeg < pend) {
        dp_cur = dpack[pbeg];
        t2cur  = T2[znl[pbeg] * HH + h];
        if (pbeg + 1 < pend) zn_n = znl[pbeg + 1];
    }

    for (int ii = pbeg; ii < pend; ++ii) {
        const float4 dp  = dp_cur;
        const float  t2v = t2cur;
        if (ii + 1 < pend) {
            dp_cur = dpack[ii + 1];
            t2cur  = T2[zn_n * HH + h];
            if (ii + 2 < pend) zn_n = znl[ii + 2];
        }

        float d = dp.w;
        float inv = 1.0f / d;
        float ux = dp.x*inv, uy = dp.y*inv, uz = dp.z*inv;
        float rc = (d < 0.5f) ? 0.5f * (fcos2pi(d) + 1.0f) : 0.0f;

        if (h < 32) {
            float en = fexp2(NEG_ALPHA_L2 * d);
            float t = en - (RBF_START + RBF_STEP * (float)h);
            rbfh[h] = (_Float16)(fexp2(NEG_BETA_L2 * t * t) * rc);
        }
        __builtin_amdgcn_wave_barrier();

        float g1 = ed1, g2 = ed2, g3 = ed3;
        const uint4* rb = (const uint4*)rbfs;
        #pragma unroll
        for (int k = 0; k < 4; ++k) {
            uint4 u = rb[k];
            h2_t b0 = u2h(u.x), b1 = u2h(u.y), b2 = u2h(u.z), b3 = u2h(u.w);
            g1 = FDOT2(AH1[4*k+0], b0, g1); g1 = FDOT2(AH1[4*k+1], b1, g1);
            g1 = FDOT2(AH1[4*k+2], b2, g1); g1 = FDOT2(AH1[4*k+3], b3, g1);
            g2 = FDOT2(AH2[4*k+0], b0, g2); g2 = FDOT2(AH2[4*k+1], b1, g2);
            g2 = FDOT2(AH2[4*k+2], b2, g2); g2 = FDOT2(AH2[4*k+3], b3, g2);
            g3 = FDOT2(AH3[4*k+0], b0, g3); g3 = FDOT2(AH3[4*k+1], b1, g3);
            g3 = FDOT2(AH3[4*k+2], b2, g3); g3 = FDOT2(AH3[4*k+3], b3, g3);
        }

        float zc = zA + t2v;
        float Cc = rc * zc;
        float f1 = g1 * Cc;
        float f2 = g2 * Cc * 10.0f;
        float f3 = g3 * Cc * 100.0f;

        Is += f1;
        sx += f2 * ux;  sy += f2 * uy;  sz += f2 * uz;
        float q = (ux*ux + uy*uy + uz*uz) * (1.0f / 3.0f);
        Sxx += f3 * (ux*ux - q);
        Syy += f3 * (uy*uy - q);
        Szz += f3 * (uz*uz - q);
        Sxy += f3 * (ux*uy);
        Sxz += f3 * (ux*uz);
        Syz += f3 * (uy*uz);
        __builtin_amdgcn_wave_barrier();
    }

    // ---- epilogue (uniform across waves; __syncthreads safe) ----
    accL[       h] = Is;
    accL[ 64  + h] = sx;  accL[128 + h] = sy;  accL[192 + h] = sz;
    accL[256 + h] = Sxx; accL[320 + h] = Syy; accL[384 + h] = Szz;
    accL[448 + h] = Sxy; accL[512 + h] = Sxz; accL[576 + h] = Syz;

    float tn = 3.0f*Is*Is + 2.0f*(sx*sx + sy*sy + sz*sz)
             + Sxx*Sxx + Syy*Syy + Szz*Szz
             + 2.0f*(Sxy*Sxy + Sxz*Sxz + Syz*Syz);

    float s1 = tn, s2 = tn * tn;
    #pragma unroll
    for (int o = 32; o > 0; o >>= 1) {
        s1 += __shfl_xor(s1, o);
        s2 += __shfl_xor(s2, o);
    }
    float mu  = s1 * (1.0f / 64.0f);
    float var = s2 * (1.0f / 64.0f) - mu * mu;
    float xh = (tn - mu) * rsqrtf(var + 1e-5f) * (WF + OFF_LNG)[h] + (WF + OFF_LNB)[h];
    nv[h] = xh;
    __syncthreads();

    #pragma unroll
    for (int jj = 0; jj < 2; ++jj) {
        int j = h + 64 * jj;
        const float4* wr = (const float4*)(WF + OFF_L1W) + j * 16;
        const float4* x4 = (const float4*)nv;
        float acc = (WF + OFF_L1B)[j];
        #pragma unroll
        for (int k4 = 0; k4 < 16; ++k4) acc += dot4(wr[k4], x4[k4]);
        y1[j] = fsilu(acc);
    }
    __syncthreads();

    #pragma unroll
    for (int mm = 0; mm < 3; ++mm) {
        int m = h + 64 * mm;
        const float4* wr = (const float4*)(WF + OFF_L2W) + m * 32;
        const float4* x4 = (const float4*)y1;
        float acc = (WF + OFF_L2B)[m];
        #pragma unroll
        for (int k4 = 0; k4 < 32; ++k4) acc += dot4(wr[k4], x4[k4]);
        y2[m] = fsilu(acc);
    }
    __syncthreads();

    float n0 = y2[3*h], n1 = y2[3*h+1], n2 = y2[3*h+2];
    const float4* t0r = (const float4*)(WF + OFF_LT0) + h * 16;
    const float4* t1r = (const float4*)(WF + OFF_LT1) + h * 16;
    const float4* t2r = (const float4*)(WF + OFF_LT2) + h * 16;
    const float4* aI  = (const float4*)(accL);
    const float4* aAx = (const float4*)(accL + 64);
    const float4* aAy = (const float4*)(accL + 128);
    const float4* aAz = (const float4*)(accL + 192);
    const float4* aXX = (const float4*)(accL + 256);
    const float4* aYY = (const float4*)(accL + 320);
    const float4* aZZ = (const float4*)(accL + 384);
    const float4* aXY = (const float4*)(accL + 448);
    const float4* aXZ = (const float4*)(accL + 512);
    const float4* aYZ = (const float4*)(accL + 576);

    float P0=0.f, PAx=0.f, PAy=0.f, PAz=0.f;
    float Q0=0.f, Q1=0.f, Q2=0.f, Q3=0.f, Q4=0.f, Q5=0.f;
    #pragma unroll
    for (int k4 = 0; k4 < 16; ++k4) {
        float4 w0 = t0r[k4], w1 = t1r[k4], w2 = t2r[k4];
        P0  += dot4(w0, aI[k4]);
        PAx += dot4(w1, aAx[k4]);
        PAy += dot4(w1, aAy[k4]);
        PAz += dot4(w1, aAz[k4]);
        Q0  += dot4(w2, aXX[k4]);
        Q1  += dot4(w2, aYY[k4]);
        Q2  += dot4(w2, aZZ[k4]);
        Q3  += dot4(w2, aXY[k4]);
        Q4  += dot4(w2, aXZ[k4]);
        Q5  += dot4(w2, aYZ[k4]);
    }
    float Iv = P0 * n0;
    float Ax = PAx * n1, Ay = PAy * n1, Az = PAz * n1;
    float Xx = Q0 * n2, Yy = Q1 * n2, Zz = Q2 * n2;
    float Xy = Q3 * n2, Xz = Q4 * n2, Yz = Q5 * n2;

    float* o = ob + h * 9;
    o[0] =  Iv + Xx;  o[1] = -Az + Xy;  o[2] =  Ay + Xz;
    o[3] =  Az + Xy;  o[4] =  Iv + Yy;  o[5] = -Ax + Yz;
    o[6] = -Ay + Xz;  o[7] =  Ax + Yz;  o[8] =  Iv + Zz;
    __syncthreads();

    float* outp = out + (size_t)n * 576;
    #pragma unroll
    for (int t = h; t < 576; t += 64) outp[t] = ob[t];
}

extern "C" void kernel_launch(void* const* d_in, const int* in_sizes, int n_in,
                              void* d_out, int out_size, void* d_ws, size_t ws_size,
                              hipStream_t stream) {
    const int* an   = (const int*)d_in[0];
    const int* pidx = (const int*)d_in[1];

    char* ws = (char*)d_ws;
    float*  WF    = (float*)(ws + WS_WF);
    int*    cnt   = (int*)(ws + WS_CNT);
    int*    offs  = (int*)(ws + WS_OFF);
    int*    cur   = (int*)(ws + WS_CUR);
    float*  T1    = (float*)(ws + WS_T1);
    float*  T2    = (float*)(ws + WS_T2);
    float4* dpack = (float4*)(ws + WS_DPK);
    int*    znl   = (int*)(ws + WS_ZNL);
    float*  out   = (float*)d_out;

    ConvArgs ca;
    for (int i = 0; i < 18; ++i) ca.src[i] = d_in[4 + i];
    ca.dst = WF;
    k_conv<<<(N_PARAMF + 255) / 256, 256, 0, stream>>>(ca, cnt);
    k_tab<<<MAXZ, 64, 0, stream>>>(WF, T1, T2);

    k_count<<<(N_PAIRS + 255) / 256, 256, 0, stream>>>(pidx, cnt);
    k_scan<<<1, 1024, 0, stream>>>(cnt, offs, cur);
    k_fill<<<(N_PAIRS + 255) / 256, 256, 0, stream>>>(pidx, an, d_in[2], d_in[3],
                                                      cur, dpack, znl);
    k_atom<<<2500, 256, 0, stream>>>(an, WF, offs, dpack, znl, T1, T2, out);
}

// Round 9
// 209.937 us; speedup vs baseline: 2.5781x; 1.9054x over previous
//
#include <hip/hip_runtime.h>
#include <hip/hip_bf16.h>

#define N_ATOMS 10000
#define N_PAIRS 100000
#define HH 64
#define MAXZ 100

typedef _Float16 h2_t __attribute__((ext_vector_type(2)));

constexpr float RBF_START = 0.6065306597126334f;
constexpr float RBF_STEP  = (1.0f - RBF_START) / 31.0f;
constexpr float RBF_BETA  = 1.0f / ((0.0625f * (1.0f - RBF_START)) * (0.0625f * (1.0f - RBF_START)));
constexpr float LOG2E     = 1.4426950408889634f;
constexpr float NEG_ALPHA_L2 = -10.0f * LOG2E;
constexpr float NEG_BETA_L2  = -RBF_BETA * LOG2E;

// ---- f32 param layout in workspace (element offsets) ----
#define OFF_EMB   0
#define OFF_W2    6400
#define OFF_B2    14592
#define OFF_D1W   14656
#define OFF_D1B   16704
#define OFF_D2W   16768
#define OFF_D2B   18816
#define OFF_D3W   18880
#define OFF_D3B   20928
#define OFF_LT0   20992
#define OFF_LT1   25088
#define OFF_LT2   29184
#define OFF_L1W   33280
#define OFF_L1B   41472
#define OFF_L2W   41600
#define OFF_L2B   66176
#define OFF_LNG   66368
#define OFF_LNB   66432
#define N_PARAMF  66496

// packed-half (uint) region layout inside PH
#define PH_DP   0        // 3 x 64 x 16 uints
#define PH_L1   3072     // 128 x 32
#define PH_L2   7168     // 192 x 64
#define PH_LT   19456    // 3 x 64 x 32
#define PH_N    25600

// ws byte offsets
#define WS_WF     0
#define WS_CNT    266240
#define WS_OFF    307200
#define WS_CUR    348160
#define WS_T1     389120
#define WS_T2     414720
#define WS_PH     440320
#define WS_DPK    542720
#define WS_ZNL    2142720
#define WS_ACCH   2542720   // 10000 x 11 x 32 uints = 14.08 MB

__device__ __forceinline__ float bf2f(unsigned short u) {
    return __uint_as_float(((unsigned int)u) << 16);
}
__device__ __forceinline__ float fexp2(float x) { return __builtin_amdgcn_exp2f(x); }
__device__ __forceinline__ float fcos2pi(float x) { return __builtin_amdgcn_cosf(x); }
__device__ __forceinline__ float fsilu(float x) { return x / (1.0f + fexp2(-LOG2E * x)); }
__device__ __forceinline__ h2_t u2h(unsigned u) { return __builtin_bit_cast(h2_t, u); }
__device__ __forceinline__ unsigned packh2(float a, float b) {
    h2_t v; v.x = (_Float16)a; v.y = (_Float16)b;
    return __builtin_bit_cast(unsigned, v);
}

#if __has_builtin(__builtin_amdgcn_fdot2)
__device__ __forceinline__ float FDOT2(h2_t a, h2_t b, float c) {
    return __builtin_amdgcn_fdot2(a, b, c, false);
}
#else
__device__ __forceinline__ float FDOT2(h2_t a, h2_t b, float c) {
    return c + (float)a.x * (float)b.x + (float)a.y * (float)b.y;
}
#endif
__device__ __forceinline__ float dot16h(const uint4* w, const uint4* x, float acc) {
    // 16 halves: one uint4 of weights vs one uint4 of rhs
    uint4 a = *w, b = *x;
    acc = FDOT2(u2h(a.x), u2h(b.x), acc);
    acc = FDOT2(u2h(a.y), u2h(b.y), acc);
    acc = FDOT2(u2h(a.z), u2h(b.z), acc);
    acc = FDOT2(u2h(a.w), u2h(b.w), acc);
    return acc;
}

// ---- buffer layout probe (round 3/4 forensics): 1 = u16/bf16 array, 0 = f32 ----
__device__ int classify64(const unsigned short* b, int lane) {
    unsigned short x = b[lane];
    int e = (x >> 7) & 0xFF;
    bool implaus = (x != 0) && (e < 96 || e > 133);
    bool zeroeven = ((lane & 1) == 0) && (x == 0);
    unsigned long long mi = __ballot(implaus);
    unsigned long long mz = __ballot(zeroeven);
    if (__popcll(mz) == 32) return 0;
    if (__popcll(mi) >= 8) return 0;
    return 1;
}

struct ConvArgs { const void* src[18]; float* dst; };

// conv (params -> f32 WF) + pair counting, fused. cnt pre-zeroed by memset.
__global__ void k_prep(ConvArgs a, const int* __restrict__ pidx, int* __restrict__ cnt) {
    const int sizes[18] = {6400,8192,64,2048,64,2048,64,2048,64,4096,4096,4096,8192,128,24576,192,64,64};
    __shared__ int fl;
    if (threadIdx.x < 64) {
        int f = classify64((const unsigned short*)a.src[0], threadIdx.x);
        if (threadIdx.x == 0) fl = f;
    }
    __syncthreads();
    int t = blockIdx.x * 256 + threadIdx.x;
    if (t < N_PARAMF) {
        int acc = 0, seg = 0, off = t;
        #pragma unroll
        for (int i = 0; i < 18; ++i) {
            if (t >= acc && t < acc + sizes[i]) { seg = i; off = t - acc; }
            acc += sizes[i];
        }
        if (fl == 1) a.dst[t] = bf2f(((const unsigned short*)a.src[seg])[off]);
        else         a.dst[t] = ((const float*)a.src[seg])[off];
    }
    if (t < N_PAIRS) atomicAdd(&cnt[pidx[t]], 1);
}

// T1/T2 tables + fp16 weight packing. grid 100 x 256 (one uint per thread).
__global__ void k_tabpack(const float* __restrict__ WF, float* __restrict__ T1,
                          float* __restrict__ T2, unsigned* __restrict__ PH) {
    int z = blockIdx.x;
    int h = threadIdx.x;
    if (h < 64) {
        const float* ez = WF + OFF_EMB + z * HH;
        const float* w2 = WF + OFF_W2 + h * 128;
        float s1 = 0.f, s2 = 0.f;
        #pragma unroll
        for (int k = 0; k < 64; ++k) {
            float e = ez[k];
            s1 += w2[k] * e;
            s2 += w2[64 + k] * e;
        }
        T1[z * HH + h] = s1;
        T2[z * HH + h] = s2;
    }
    int q = blockIdx.x * 256 + threadIdx.x;   // 0..25599
    int src;
    if (q < PH_L1) {
        int w = q >> 10, r = q & 1023;
        src = (w == 0 ? OFF_D1W : (w == 1 ? OFF_D2W : OFF_D3W)) + r * 2;
    } else if (q < PH_L2) {
        src = OFF_L1W + (q - PH_L1) * 2;
    } else if (q < PH_LT) {
        src = OFF_L2W + (q - PH_L2) * 2;
    } else {
        src = OFF_LT0 + (q - PH_LT) * 2;      // lt0/lt1/lt2 contiguous
    }
    PH[q] = packh2(WF[src], WF[src + 1]);
}

__global__ void k_scan(const int* __restrict__ cnt, int* __restrict__ offs, int* __restrict__ cur) {
    __shared__ int buf[1024];
    int tid = threadIdx.x;
    int base = tid * 10;
    int c[10]; int s = 0;
    #pragma unroll
    for (int i = 0; i < 10; ++i) {
        int idx = base + i;
        int v = (idx < N_ATOMS) ? cnt[idx] : 0;
        c[i] = v; s += v;
    }
    buf[tid] = s;
    __syncthreads();
    for (int off = 1; off < 1024; off <<= 1) {
        int v = (tid >= off) ? buf[tid - off] : 0;
        __syncthreads();
        buf[tid] += v;
        __syncthreads();
    }
    int run = buf[tid] - s;
    #pragma unroll
    for (int i = 0; i < 10; ++i) {
        int idx = base + i;
        if (idx < N_ATOMS) { offs[idx] = run; cur[idx] = run; run += c[i]; }
    }
    if (tid == 0) offs[N_ATOMS] = N_PAIRS;
}

__global__ void k_fill(const int* __restrict__ pidx, const int* __restrict__ an,
                       const void* __restrict__ dij_v, const void* __restrict__ rij_v,
                       int* __restrict__ cur,
                       float4* __restrict__ dpack, int* __restrict__ znl) {
    __shared__ int fdr[2];
    if (threadIdx.x < 64) {
        int fd = classify64((const unsigned short*)dij_v, threadIdx.x);
        int fr = classify64((const unsigned short*)rij_v, threadIdx.x);
        if (threadIdx.x == 0) { fdr[0] = fd; fdr[1] = fr; }
    }
    __syncthreads();
    int p = blockIdx.x * 256 + threadIdx.x;
    if (p >= N_PAIRS) return;
    int s = pidx[p];
    int dst = pidx[N_PAIRS + p];
    int pos = atomicAdd(&cur[s], 1);
    float d, rx, ry, rz;
    if (fdr[0] == 1) d = bf2f(((const unsigned short*)dij_v)[p]);
    else             d = ((const float*)dij_v)[p];
    if (fdr[1] == 1) {
        const unsigned short* r = (const unsigned short*)rij_v;
        rx = bf2f(r[3*p]); ry = bf2f(r[3*p+1]); rz = bf2f(r[3*p+2]);
    } else {
        const float* r = (const float*)rij_v;
        rx = r[3*p]; ry = r[3*p+1]; rz = r[3*p+2];
    }
    dpack[pos] = make_float4(rx, ry, rz, d);
    znl[pos] = an[dst];
}

// Pair accumulation: 4 waves/block, 1 atom/wave, dp weights LDS-staged fp16.
// Row stride 20 uints (80 B): stride/4 = 4*odd mod 32 -> conflict-free b128.
__global__ __launch_bounds__(256, 4) void k_pair(
    const int* __restrict__ an,
    const float* __restrict__ WF,
    const int* __restrict__ offs,
    const float4* __restrict__ dpack, const int* __restrict__ znl,
    const float* __restrict__ T1, const float* __restrict__ T2,
    const unsigned* __restrict__ PH,
    unsigned* __restrict__ accH)
{
    __shared__ __align__(16) unsigned dpL[3 * 1280];
    __shared__ __align__(16) unsigned rbq[4 * 16];

    // stage dp weights (3072 uints) into padded LDS
    for (int q = threadIdx.x; q < 3072; q += 256) {
        int w = q >> 10, r = q & 1023;
        int hh = r >> 4, u = r & 15;
        dpL[w * 1280 + hh * 20 + u] = PH[PH_DP + q];
    }
    __syncthreads();

    const int wave = threadIdx.x >> 6;
    const int h    = threadIdx.x & 63;
    const int n    = blockIdx.x * 4 + wave;

    _Float16* rbfh = (_Float16*)&rbq[wave * 16];
    const uint4* w1p = (const uint4*)&dpL[0 * 1280 + h * 20];
    const uint4* w2p = (const uint4*)&dpL[1 * 1280 + h * 20];
    const uint4* w3p = (const uint4*)&dpL[2 * 1280 + h * 20];
    const uint4* rbp = (const uint4*)&rbq[wave * 16];

    const float ed1 = (WF + OFF_D1B)[h];
    const float ed2 = (WF + OFF_D2B)[h];
    const float ed3 = (WF + OFF_D3B)[h];
    const float zA  = (WF + OFF_B2)[h] + T1[an[n] * HH + h];

    float Is=0.f, sx=0.f, sy=0.f, sz=0.f;
    float Sxx=0.f, Syy=0.f, Szz=0.f, Sxy=0.f, Sxz=0.f, Syz=0.f;

    const int pbeg = offs[n], pend = offs[n + 1];

    float4 dp_cur = make_float4(0.f, 0.f, 0.f, 1.f);
    float  t2cur  = 0.f;
    int    zn_n   = 0;
    if (pbeg < pend) {
        dp_cur = dpack[pbeg];
        t2cur  = T2[znl[pbeg] * HH + h];
        if (pbeg + 1 < pend) zn_n = znl[pbeg + 1];
    }

    for (int ii = pbeg; ii < pend; ++ii) {
        const float4 dpv = dp_cur;
        const float  t2v = t2cur;
        if (ii + 1 < pend) {
            dp_cur = dpack[ii + 1];
            t2cur  = T2[zn_n * HH + h];
            if (ii + 2 < pend) zn_n = znl[ii + 2];
        }

        float d = dpv.w;
        float inv = 1.0f / d;
        float ux = dpv.x*inv, uy = dpv.y*inv, uz = dpv.z*inv;
        float rc = (d < 0.5f) ? 0.5f * (fcos2pi(d) + 1.0f) : 0.0f;

        if (h < 32) {
            float en = fexp2(NEG_ALPHA_L2 * d);
            float t = en - (RBF_START + RBF_STEP * (float)h);
            rbfh[h] = (_Float16)(fexp2(NEG_BETA_L2 * t * t) * rc);
        }
        __builtin_amdgcn_wave_barrier();

        float g1 = ed1, g2 = ed2, g3 = ed3;
        #pragma unroll
        for (int k = 0; k < 4; ++k) {
            g1 = dot16h(w1p + k, rbp + k, g1);
            g2 = dot16h(w2p + k, rbp + k, g2);
            g3 = dot16h(w3p + k, rbp + k, g3);
        }

        float zc = zA + t2v;
        float Cc = rc * zc;
        float f1 = g1 * Cc;
        float f2 = g2 * Cc * 10.0f;
        float f3 = g3 * Cc * 100.0f;

        Is += f1;
        sx += f2 * ux;  sy += f2 * uy;  sz += f2 * uz;
        float q = (ux*ux + uy*uy + uz*uz) * (1.0f / 3.0f);
        Sxx += f3 * (ux*ux - q);
        Syy += f3 * (uy*uy - q);
        Szz += f3 * (uz*uz - q);
        Sxy += f3 * (ux*uy);
        Sxz += f3 * (ux*uz);
        Syz += f3 * (uy*uz);
        __builtin_amdgcn_wave_barrier();
    }

    // tn + LayerNorm (f32, before any fp16 rounding)
    float tn = 3.0f*Is*Is + 2.0f*(sx*sx + sy*sy + sz*sz)
             + Sxx*Sxx + Syy*Syy + Szz*Szz
             + 2.0f*(Sxy*Sxy + Sxz*Sxz + Syz*Syz);
    float s1 = tn, s2 = tn * tn;
    #pragma unroll
    for (int o = 32; o > 0; o >>= 1) {
        s1 += __shfl_xor(s1, o);
        s2 += __shfl_xor(s2, o);
    }
    float mu  = s1 * (1.0f / 64.0f);
    float var = s2 * (1.0f / 64.0f) - mu * mu;
    float nv  = (tn - mu) * rsqrtf(var + 1e-5f) * (WF + OFF_LNG)[h] + (WF + OFF_LNB)[h];

    // pack 11 vectors (10 accums + nv) to fp16 pairs; even lanes store
    float vals[11] = {Is, sx, sy, sz, Sxx, Syy, Szz, Sxy, Sxz, Syz, nv};
    #pragma unroll
    for (int c = 0; c < 11; ++c) {
        float pv = __shfl_xor(vals[c], 1);
        if ((h & 1) == 0)
            accH[((n * 11 + c) << 5) + (h >> 1)] = packh2(vals[c], pv);
    }
}

// Epilogue: MLP + transform. ls2 fp16 in LDS (stride 68 uints, conflict-free);
// ls1/lt fp16 from global (L1-resident). 2 blocks/CU.
__global__ __launch_bounds__(256, 2) void k_post(
    const float* __restrict__ WF,
    const unsigned* __restrict__ PH,
    const unsigned* __restrict__ accH,
    float* __restrict__ out)
{
    __shared__ __align__(16) unsigned wL2[192 * 68];    // 52224 B
    __shared__ __align__(16) unsigned acch[4][12 * 32]; // per-wave: 11 vecs (+pad)
    __shared__ __align__(16) unsigned y1h[4][64];
    __shared__ __align__(16) unsigned y2h[4][96];

    for (int q = threadIdx.x; q < 12288; q += 256) {
        int m = q >> 6, u = q & 63;
        wL2[m * 68 + u] = PH[PH_L2 + q];
    }
    __syncthreads();

    const int wave = threadIdx.x >> 6;
    const int h    = threadIdx.x & 63;
    const int gw   = blockIdx.x * 4 + wave;
    const int GW   = gridDim.x * 4;

    const uint4* l1base = (const uint4*)(PH + PH_L1);
    const uint4* lt0 = (const uint4*)(PH + PH_LT) + h * 8;
    const uint4* lt1 = (const uint4*)(PH + PH_LT + 2048) + h * 8;
    const uint4* lt2 = (const uint4*)(PH + PH_LT + 4096) + h * 8;

    for (int n = gw; n < N_ATOMS; n += GW) {
        // stage this atom's 11 fp16 vectors
        if (h < 32) {
            #pragma unroll
            for (int c = 0; c < 11; ++c)
                acch[wave][c * 32 + h] = accH[((n * 11 + c) << 5) + h];
        }
        __builtin_amdgcn_wave_barrier();

        const uint4* nvh = (const uint4*)&acch[wave][10 * 32];

        // y1 = silu(ls1_w @ nv + b1): j = h, h+64
        float ya = (WF + OFF_L1B)[h];
        float yb = (WF + OFF_L1B)[h + 64];
        {
            const uint4* ra = l1base + h * 8;
            const uint4* rb = l1base + (h + 64) * 8;
            #pragma unroll
            for (int k = 0; k < 8; ++k) {
                ya = dot16h(ra + k, nvh + k, ya);
                yb = dot16h(rb + k, nvh + k, yb);
            }
        }
        ya = fsilu(ya); yb = fsilu(yb);
        {
            float pa = __shfl_xor(ya, 1);
            float pb = __shfl_xor(yb, 1);
            if ((h & 1) == 0) {
                y1h[wave][(h >> 1)]      = packh2(ya, pa);
                y1h[wave][32 + (h >> 1)] = packh2(yb, pb);
            }
        }
        __builtin_amdgcn_wave_barrier();

        // y2 = silu(ls2_w @ y1 + b2): m = h, h+64, h+128
        const uint4* y1p = (const uint4*)&y1h[wave][0];
        float z0 = (WF + OFF_L2B)[h];
        float z1 = (WF + OFF_L2B)[h + 64];
        float z2 = (WF + OFF_L2B)[h + 128];
        {
            const uint4* r0 = (const uint4*)&wL2[(h)       * 68];
            const uint4* r1 = (const uint4*)&wL2[(h + 64)  * 68];
            const uint4* r2 = (const uint4*)&wL2[(h + 128) * 68];
            #pragma unroll
            for (int k = 0; k < 16; ++k) {
                uint4 x = y1p[k];
                uint4 a0 = r0[k], a1 = r1[k], a2 = r2[k];
                z0 = FDOT2(u2h(a0.x), u2h(x.x), z0); z0 = FDOT2(u2h(a0.y), u2h(x.y), z0);
                z0 = FDOT2(u2h(a0.z), u2h(x.z), z0); z0 = FDOT2(u2h(a0.w), u2h(x.w), z0);
                z1 = FDOT2(u2h(a1.x), u2h(x.x), z1); z1 = FDOT2(u2h(a1.y), u2h(x.y), z1);
                z1 = FDOT2(u2h(a1.z), u2h(x.z), z1); z1 = FDOT2(u2h(a1.w), u2h(x.w), z1);
                z2 = FDOT2(u2h(a2.x), u2h(x.x), z2); z2 = FDOT2(u2h(a2.y), u2h(x.y), z2);
                z2 = FDOT2(u2h(a2.z), u2h(x.z), z2); z2 = FDOT2(u2h(a2.w), u2h(x.w), z2);
            }
        }
        z0 = fsilu(z0); z1 = fsilu(z1); z2 = fsilu(z2);
        {
            float p0 = __shfl_xor(z0, 1);
            float p1 = __shfl_xor(z1, 1);
            float p2 = __shfl_xor(z2, 1);
            if ((h & 1) == 0) {
                y2h[wave][(h >> 1)]      = packh2(z0, p0);
                y2h[wave][32 + (h >> 1)] = packh2(z1, p1);
                y2h[wave][64 + (h >> 1)] = packh2(z2, p2);
            }
        }
        __builtin_amdgcn_wave_barrier();

        // norm multipliers n0..n2 = y2[3h..3h+2]
        float n0, n1, n2;
        {
            int i0 = 3 * h;
            unsigned u0 = y2h[wave][i0 >> 1];
            unsigned u1 = y2h[wave][(i0 >> 1) + 1];
            h2_t a = u2h(u0), b = u2h(u1);
            if (i0 & 1) { n0 = (float)a.y; n1 = (float)b.x; n2 = (float)b.y; }
            else        { n0 = (float)a.x; n1 = (float)a.y; n2 = (float)b.x; }
        }

        // transform: 10 dot64 against lt rows
        const uint4* aI  = (const uint4*)&acch[wave][0];
        const uint4* aAx = (const uint4*)&acch[wave][32];
        const uint4* aAy = (const uint4*)&acch[wave][64];
        const uint4* aAz = (const uint4*)&acch[wave][96];
        const uint4* aXX = (const uint4*)&acch[wave][128];
        const uint4* aYY = (const uint4*)&acch[wave][160];
        const uint4* aZZ = (const uint4*)&acch[wave][192];
        const uint4* aXY = (const uint4*)&acch[wave][224];
        const uint4* aXZ = (const uint4*)&acch[wave][256];
        const uint4* aYZ = (const uint4*)&acch[wave][288];

        float P0=0.f, PAx=0.f, PAy=0.f, PAz=0.f;
        float Q0=0.f, Q1=0.f, Q2=0.f, Q3=0.f, Q4=0.f, Q5=0.f;
        #pragma unroll
        for (int k = 0; k < 8; ++k) {
            P0  = dot16h(lt0 + k, aI  + k, P0);
            PAx = dot16h(lt1 + k, aAx + k, PAx);
            PAy = dot16h(lt1 + k, aAy + k, PAy);
            PAz = dot16h(lt1 + k, aAz + k, PAz);
            Q0  = dot16h(lt2 + k, aXX + k, Q0);
            Q1  = dot16h(lt2 + k, aYY + k, Q1);
            Q2  = dot16h(lt2 + k, aZZ + k, Q2);
            Q3  = dot16h(lt2 + k, aXY + k, Q3);
            Q4  = dot16h(lt2 + k, aXZ + k, Q4);
            Q5  = dot16h(lt2 + k, aYZ + k, Q5);
        }
        float Iv = P0 * n0;
        float Ax = PAx * n1, Ay = PAy * n1, Az = PAz * n1;
        float Xx = Q0 * n2, Yy = Q1 * n2, Zz = Q2 * n2;
        float Xy = Q3 * n2, Xz = Q4 * n2, Yz = Q5 * n2;

        float* o = out + (size_t)n * 576 + h * 9;
        o[0] =  Iv + Xx;  o[1] = -Az + Xy;  o[2] =  Ay + Xz;
        o[3] =  Az + Xy;  o[4] =  Iv + Yy;  o[5] = -Ax + Yz;
        o[6] = -Ay + Xz;  o[7] =  Ax + Yz;  o[8] =  Iv + Zz;
        __builtin_amdgcn_wave_barrier();
    }
}

extern "C" void kernel_launch(void* const* d_in, const int* in_sizes, int n_in,
                              void* d_out, int out_size, void* d_ws, size_t ws_size,
                              hipStream_t stream) {
    const int* an   = (const int*)d_in[0];
    const int* pidx = (const int*)d_in[1];

    char* ws = (char*)d_ws;
    float*    WF    = (float*)(ws + WS_WF);
    int*      cnt   = (int*)(ws + WS_CNT);
    int*      offs  = (int*)(ws + WS_OFF);
    int*      cur   = (int*)(ws + WS_CUR);
    float*    T1    = (float*)(ws + WS_T1);
    float*    T2    = (float*)(ws + WS_T2);
    unsigned* PH    = (unsigned*)(ws + WS_PH);
    float4*   dpack = (float4*)(ws + WS_DPK);
    int*      znl   = (int*)(ws + WS_ZNL);
    unsigned* accH  = (unsigned*)(ws + WS_ACCH);
    float*    out   = (float*)d_out;

    hipMemsetAsync(cnt, 0, N_ATOMS * sizeof(int), stream);

    ConvArgs ca;
    for (int i = 0; i < 18; ++i) ca.src[i] = d_in[4 + i];
    ca.dst = WF;
    k_prep<<<(N_PAIRS + 255) / 256, 256, 0, stream>>>(ca, pidx, cnt);
    k_tabpack<<<100, 256, 0, stream>>>(WF, T1, T2, PH);
    k_scan<<<1, 1024, 0, stream>>>(cnt, offs, cur);
    k_fill<<<(N_PAIRS + 255) / 256, 256, 0, stream>>>(pidx, an, d_in[2], d_in[3],
                                                      cur, dpack, znl);
    k_pair<<<2500, 256, 0, stream>>>(an, WF, offs, dpack, znl, T1, T2, PH, accH);
    k_post<<<256, 256, 0, stream>>>(WF, PH, accH, out);
}